// Round 1
// baseline (3304.490 us; speedup 1.0000x reference)
//
#include <hip/hip_runtime.h>
#include <hip/hip_bf16.h>

// Problem constants
#define NPTS   65536
#define BATCH  8
#define CH     64
#define RES    32
#define RCELLS 32768          // 32^3
#define NEG_SLOPE 0.1f
#define BN_EPS 1e-4f

// Workspace layout (float offsets)
#define OFF_SUMS   0                                // 24 floats (B*3)
#define OFF_SCALE  24                               // 8 uints
#define OFF_CNT    32                               // B*32768 floats
#define OFF_IDX    (OFF_CNT + BATCH*RCELLS)         // B*N ints
#define OFF_NORM   (OFF_IDX + BATCH*NPTS)           // B*3*N floats
#define OFF_WT1    (OFF_NORM + BATCH*3*NPTS)        // 64*64*27
#define OFF_WT2    (OFF_WT1 + 110592)
#define OFF_BN     (OFF_WT2 + 110592)               // 4*64
#define OFF_G1     (OFF_BN + 256)                   // B*64*32768
#define OFF_G2     (OFF_G1 + BATCH*CH*RCELLS)

__device__ inline float waveReduceSum(float v) {
#pragma unroll
    for (int off = 32; off > 0; off >>= 1) v += __shfl_down(v, off, 64);
    return v;
}
__device__ inline float waveReduceMax(float v) {
#pragma unroll
    for (int off = 32; off > 0; off >>= 1) v = fmaxf(v, __shfl_down(v, off, 64));
    return v;
}

// ---------------- per-batch coordinate sums ----------------
__global__ __launch_bounds__(256) void k_stats_sum(const float* __restrict__ coords,
                                                   float* __restrict__ sums) {
    __shared__ float sm[3][4];
    int b = blockIdx.x >> 3, chunk = blockIdx.x & 7;
    const float* cb = coords + (size_t)b * 3 * NPTS;
    float s0 = 0.f, s1 = 0.f, s2 = 0.f;
    for (int i = threadIdx.x; i < 8192; i += 256) {
        int n = chunk * 8192 + i;
        s0 += cb[n];
        s1 += cb[n + NPTS];
        s2 += cb[n + 2 * NPTS];
    }
    s0 = waveReduceSum(s0); s1 = waveReduceSum(s1); s2 = waveReduceSum(s2);
    int lane = threadIdx.x & 63, wid = threadIdx.x >> 6;
    if (lane == 0) { sm[0][wid] = s0; sm[1][wid] = s1; sm[2][wid] = s2; }
    __syncthreads();
    if (threadIdx.x == 0) {
        atomicAdd(&sums[b * 3 + 0], sm[0][0] + sm[0][1] + sm[0][2] + sm[0][3]);
        atomicAdd(&sums[b * 3 + 1], sm[1][0] + sm[1][1] + sm[1][2] + sm[1][3]);
        atomicAdd(&sums[b * 3 + 2], sm[2][0] + sm[2][1] + sm[2][2] + sm[2][3]);
    }
}

// ---------------- per-batch max ||coord - mean|| ----------------
__global__ __launch_bounds__(256) void k_stats_max(const float* __restrict__ coords,
                                                   const float* __restrict__ sums,
                                                   unsigned int* __restrict__ scaleBits) {
    __shared__ float sm[4];
    int b = blockIdx.x >> 3, chunk = blockIdx.x & 7;
    const float* cb = coords + (size_t)b * 3 * NPTS;
    float mx = sums[b * 3 + 0] * (1.f / NPTS);
    float my = sums[b * 3 + 1] * (1.f / NPTS);
    float mz = sums[b * 3 + 2] * (1.f / NPTS);
    float m = 0.f;
    for (int i = threadIdx.x; i < 8192; i += 256) {
        int n = chunk * 8192 + i;
        float dx = cb[n] - mx, dy = cb[n + NPTS] - my, dz = cb[n + 2 * NPTS] - mz;
        m = fmaxf(m, sqrtf(dx * dx + dy * dy + dz * dz));
    }
    m = waveReduceMax(m);
    int lane = threadIdx.x & 63, wid = threadIdx.x >> 6;
    if (lane == 0) sm[wid] = m;
    __syncthreads();
    if (threadIdx.x == 0) {
        float r = fmaxf(fmaxf(sm[0], sm[1]), fmaxf(sm[2], sm[3]));
        atomicMax(&scaleBits[b], __float_as_uint(r));
    }
}

// ---------------- normalized coords, voxel index, counts ----------------
__global__ __launch_bounds__(256) void k_vox_assign(const float* __restrict__ coords,
                                                    const float* __restrict__ sums,
                                                    const unsigned int* __restrict__ scaleBits,
                                                    float* __restrict__ normc,
                                                    int* __restrict__ idxb,
                                                    float* __restrict__ cnt) {
    int g = blockIdx.x * 256 + threadIdx.x;       // 0 .. B*N-1
    int b = g >> 16, n = g & (NPTS - 1);
    const float* cb = coords + (size_t)b * 3 * NPTS;
    float scale2 = __uint_as_float(scaleBits[b]) * 2.f;
    int v[3];
#pragma unroll
    for (int d = 0; d < 3; ++d) {
        float mean = sums[b * 3 + d] * (1.f / NPTS);
        float x = (cb[d * NPTS + n] - mean) / scale2 + 0.5f;
        x *= (float)RES;
        x = fminf(fmaxf(x, 0.f), (float)(RES - 1));
        normc[(size_t)b * 3 * NPTS + d * NPTS + n] = x;
        v[d] = (int)rintf(x);
    }
    int id = (v[0] * RES + v[1]) * RES + v[2];
    idxb[b * NPTS + n] = id;
    atomicAdd(&cnt[b * RCELLS + id], 1.f);
}

// ---------------- weight transpose + BN constants ----------------
__global__ __launch_bounds__(256) void k_prep(const float* __restrict__ w,
                                              const float* __restrict__ bias,
                                              const float* __restrict__ g,
                                              const float* __restrict__ be,
                                              const float* __restrict__ m,
                                              const float* __restrict__ v,
                                              float* __restrict__ wT,
                                              float* __restrict__ bnA,
                                              float* __restrict__ bnB) {
    int s = blockIdx.x * 256 + threadIdx.x;       // 0 .. 110591
    if (s < 64 * 64 * 27) {
        int co = s & 63;
        int r = s >> 6;                            // ci*27 + tap
        wT[s] = w[co * 1728 + r];
    }
    if (s < 64) {
        float A = g[s] / sqrtf(v[s] + BN_EPS);
        bnA[s] = A;
        bnB[s] = (bias[s] - m[s]) * A + be[s];
    }
}

// ---------------- scatter-average into voxel grid ----------------
__global__ __launch_bounds__(256) void k_scatter(const float* __restrict__ features,
                                                 const int* __restrict__ idxb,
                                                 const float* __restrict__ cnt,
                                                 float* __restrict__ grid) {
    __shared__ float cells[16384];                 // 64 KiB
    int bc = blockIdx.x >> 1;
    int half = blockIdx.x & 1;
    int b = bc >> 6, c = bc & 63;
    int tid = threadIdx.x;
    for (int i = tid; i < 16384; i += 256) cells[i] = 0.f;
    __syncthreads();
    const float* f = features + ((size_t)b * CH + c) * NPTS;
    const int* id = idxb + b * NPTS;
    int lo = half * 16384;
    for (int n = tid; n < NPTS; n += 256) {
        int cell = id[n] - lo;
        if ((unsigned)cell < 16384u) atomicAdd(&cells[cell], f[n]);
    }
    __syncthreads();
    const float* cb = cnt + b * RCELLS + lo;
    float* gout = grid + ((size_t)b * CH + c) * RCELLS + lo;
    for (int i = tid; i < 16384; i += 256)
        gout[i] = cells[i] / fmaxf(cb[i], 1.f);
}

// ---------------- 3x3x3 conv + BN + LeakyReLU ----------------
// Block: one (b, z-plane, cog of 16 c_out). Thread: 8 c_out x 8 voxels.
#define IN_ROW   33
#define IN_PLANE (IN_ROW * 32)                     // 1056
__global__ __launch_bounds__(256) void k_conv(const float* __restrict__ in,
                                              float* __restrict__ out,
                                              const float* __restrict__ wT,
                                              const float* __restrict__ bnA,
                                              const float* __restrict__ bnB) {
    __shared__ float sIn[3 * IN_PLANE];            // 3 padded z-planes for one ci
    __shared__ float sW[432];                      // 27 taps x 16 c_out
    int bi = blockIdx.x;
    int b = bi >> 7;
    int rem = bi & 127;
    int z = rem >> 2;
    int cog = rem & 3;
    int tid = threadIdx.x;
    int co_half = tid >> 7;                        // 0 or 1
    int tv = tid & 127;
    int y = tv >> 2;
    int x0 = (tv & 3) << 3;

    float acc[8][8];
#pragma unroll
    for (int cc = 0; cc < 8; ++cc)
#pragma unroll
        for (int j = 0; j < 8; ++j) acc[cc][j] = 0.f;

    const float* inb = in + (size_t)b * CH * RCELLS;

    for (int ci = 0; ci < CH; ++ci) {
        // stage 3 z-planes (zero pad at boundaries) into padded LDS
#pragma unroll
        for (int t4 = 0; t4 < 3; ++t4) {
            int s = tid + t4 * 256;                // 0..767 (float4 id)
            int p = s >> 8;
            int off4 = s & 255;
            int row = off4 >> 3;
            int col = (off4 & 7) << 2;
            int zp = z - 1 + p;
            float4 val = {0.f, 0.f, 0.f, 0.f};
            if (zp >= 0 && zp < RES)
                val = *(const float4*)(inb + (size_t)ci * RCELLS + zp * 1024 + off4 * 4);
            int dst = p * IN_PLANE + row * IN_ROW + col;
            sIn[dst + 0] = val.x; sIn[dst + 1] = val.y;
            sIn[dst + 2] = val.z; sIn[dst + 3] = val.w;
        }
        // stage weights: sW[tap*16 + col] for 16 c_out of this cog
        for (int s = tid; s < 432; s += 256) {
            int tap = s >> 4;
            int col = s & 15;
            sW[s] = wT[(ci * 27 + tap) * 64 + cog * 16 + col];
        }
        __syncthreads();

#pragma unroll
        for (int p = 0; p < 3; ++p) {
#pragma unroll
            for (int dy = -1; dy <= 1; ++dy) {
                int yy = y + dy;
                float r[10];
                if (yy >= 0 && yy < RES) {
                    const float* row = &sIn[p * IN_PLANE + yy * IN_ROW + x0];
                    r[0] = (x0 > 0) ? row[-1] : 0.f;
#pragma unroll
                    for (int j = 0; j < 8; ++j) r[j + 1] = row[j];
                    r[9] = (x0 < 24) ? row[8] : 0.f;
                } else {
#pragma unroll
                    for (int j = 0; j < 10; ++j) r[j] = 0.f;
                }
#pragma unroll
                for (int dx = 0; dx < 3; ++dx) {
                    const float* wp = &sW[(p * 9 + (dy + 1) * 3 + dx) * 16 + co_half * 8];
#pragma unroll
                    for (int cc = 0; cc < 8; ++cc) {
                        float wv = wp[cc];
#pragma unroll
                        for (int j = 0; j < 8; ++j)
                            acc[cc][j] = fmaf(wv, r[j + dx], acc[cc][j]);
                    }
                }
            }
        }
        __syncthreads();
    }

    // epilogue: BN + LeakyReLU, store
    int vbase = z * 1024 + y * 32 + x0;
#pragma unroll
    for (int cc = 0; cc < 8; ++cc) {
        int co = cog * 16 + co_half * 8 + cc;
        float A = bnA[co], Bc = bnB[co];
        float* op = out + ((size_t)b * CH + co) * RCELLS + vbase;
        float4 o0, o1;
        float t;
        t = acc[cc][0] * A + Bc; o0.x = (t >= 0.f) ? t : NEG_SLOPE * t;
        t = acc[cc][1] * A + Bc; o0.y = (t >= 0.f) ? t : NEG_SLOPE * t;
        t = acc[cc][2] * A + Bc; o0.z = (t >= 0.f) ? t : NEG_SLOPE * t;
        t = acc[cc][3] * A + Bc; o0.w = (t >= 0.f) ? t : NEG_SLOPE * t;
        t = acc[cc][4] * A + Bc; o1.x = (t >= 0.f) ? t : NEG_SLOPE * t;
        t = acc[cc][5] * A + Bc; o1.y = (t >= 0.f) ? t : NEG_SLOPE * t;
        t = acc[cc][6] * A + Bc; o1.z = (t >= 0.f) ? t : NEG_SLOPE * t;
        t = acc[cc][7] * A + Bc; o1.w = (t >= 0.f) ? t : NEG_SLOPE * t;
        *(float4*)op = o0;
        *(float4*)(op + 4) = o1;
    }
}

// ---------------- trilinear devoxelize ----------------
__global__ __launch_bounds__(256) void k_devox(const float* __restrict__ grid,
                                               const float* __restrict__ normc,
                                               float* __restrict__ out) {
    int g = blockIdx.x * 256 + threadIdx.x;        // 0 .. B*N-1
    int b = g >> 16, n = g & (NPTS - 1);
    const float* nb = normc + (size_t)b * 3 * NPTS;
    float tx = nb[n], ty = nb[NPTS + n], tz = nb[2 * NPTS + n];
    float lx = floorf(tx), ly = floorf(ty), lz = floorf(tz);
    float fx = tx - lx, fy = ty - ly, fz = tz - lz;
    int x0 = (int)lx, y0 = (int)ly, z0 = (int)lz;
    int x1 = min(x0 + 1, RES - 1), y1 = min(y0 + 1, RES - 1), z1 = min(z0 + 1, RES - 1);
    int i000 = (x0 * RES + y0) * RES + z0;
    int i001 = (x0 * RES + y0) * RES + z1;
    int i010 = (x0 * RES + y1) * RES + z0;
    int i011 = (x0 * RES + y1) * RES + z1;
    int i100 = (x1 * RES + y0) * RES + z0;
    int i101 = (x1 * RES + y0) * RES + z1;
    int i110 = (x1 * RES + y1) * RES + z0;
    int i111 = (x1 * RES + y1) * RES + z1;
    float gx = 1.f - fx, gy = 1.f - fy, gz = 1.f - fz;
    float w000 = gx * gy * gz, w001 = gx * gy * fz;
    float w010 = gx * fy * gz, w011 = gx * fy * fz;
    float w100 = fx * gy * gz, w101 = fx * gy * fz;
    float w110 = fx * fy * gz, w111 = fx * fy * fz;
    const float* gb = grid + (size_t)b * CH * RCELLS;
    float* ob = out + (size_t)b * CH * NPTS + n;
#pragma unroll 2
    for (int c = 0; c < CH; ++c) {
        const float* gc = gb + (size_t)c * RCELLS;
        float acc = w000 * gc[i000] + w001 * gc[i001] + w010 * gc[i010] + w011 * gc[i011]
                  + w100 * gc[i100] + w101 * gc[i101] + w110 * gc[i110] + w111 * gc[i111];
        ob[(size_t)c * NPTS] = acc;
    }
}

extern "C" void kernel_launch(void* const* d_in, const int* in_sizes, int n_in,
                              void* d_out, int out_size, void* d_ws, size_t ws_size,
                              hipStream_t stream) {
    const float* features = (const float*)d_in[0];
    const float* coords   = (const float*)d_in[1];
    const float* w1  = (const float*)d_in[2];
    const float* b1  = (const float*)d_in[3];
    const float* g1  = (const float*)d_in[4];
    const float* be1 = (const float*)d_in[5];
    const float* m1  = (const float*)d_in[6];
    const float* v1  = (const float*)d_in[7];
    const float* w2  = (const float*)d_in[8];
    const float* b2  = (const float*)d_in[9];
    const float* g2  = (const float*)d_in[10];
    const float* be2 = (const float*)d_in[11];
    const float* m2  = (const float*)d_in[12];
    const float* v2  = (const float*)d_in[13];

    float* ws = (float*)d_ws;
    float*        sums      = ws + OFF_SUMS;
    unsigned int* scaleBits = (unsigned int*)(ws + OFF_SCALE);
    float*        cnt       = ws + OFF_CNT;
    int*          idxb      = (int*)(ws + OFF_IDX);
    float*        normc     = ws + OFF_NORM;
    float*        wT1       = ws + OFF_WT1;
    float*        wT2       = ws + OFF_WT2;
    float*        bnA1      = ws + OFF_BN;
    float*        bnB1      = ws + OFF_BN + 64;
    float*        bnA2      = ws + OFF_BN + 128;
    float*        bnB2      = ws + OFF_BN + 192;
    float*        grid1     = ws + OFF_G1;
    float*        grid2     = ws + OFF_G2;

    // zero: sums + scaleBits + cnt
    hipMemsetAsync(ws, 0, (size_t)(OFF_CNT + BATCH * RCELLS) * sizeof(float), stream);

    k_stats_sum<<<64, 256, 0, stream>>>(coords, sums);
    k_stats_max<<<64, 256, 0, stream>>>(coords, sums, scaleBits);
    k_vox_assign<<<(BATCH * NPTS) / 256, 256, 0, stream>>>(coords, sums, scaleBits,
                                                           normc, idxb, cnt);
    k_prep<<<432, 256, 0, stream>>>(w1, b1, g1, be1, m1, v1, wT1, bnA1, bnB1);
    k_prep<<<432, 256, 0, stream>>>(w2, b2, g2, be2, m2, v2, wT2, bnA2, bnB2);
    k_scatter<<<BATCH * CH * 2, 256, 0, stream>>>(features, idxb, cnt, grid1);
    k_conv<<<BATCH * RES * 4, 256, 0, stream>>>(grid1, grid2, wT1, bnA1, bnB1);
    k_conv<<<BATCH * RES * 4, 256, 0, stream>>>(grid2, grid1, wT2, bnA2, bnB2);
    k_devox<<<(BATCH * NPTS) / 256, 256, 0, stream>>>(grid1, normc, (float*)d_out);

    // append passthrough coords
    hipMemcpyAsync((float*)d_out + (size_t)BATCH * CH * NPTS, coords,
                   (size_t)BATCH * 3 * NPTS * sizeof(float),
                   hipMemcpyDeviceToDevice, stream);
}

// Round 2
// 987.133 us; speedup vs baseline: 3.3476x; 3.3476x over previous
//
#include <hip/hip_runtime.h>
#include <hip/hip_bf16.h>

// Problem constants
#define NPTS   65536
#define BATCH  8
#define CH     64
#define RES    32
#define RCELLS 32768          // 32^3
#define NEG_SLOPE 0.1f
#define BN_EPS 1e-4f

typedef float    f32x4 __attribute__((ext_vector_type(4)));
typedef _Float16 f16x8 __attribute__((ext_vector_type(8)));
typedef _Float16 f16x4 __attribute__((ext_vector_type(4)));

// Workspace layout (float offsets)
#define OFF_SUMS   0                                // 24 floats
#define OFF_SCALE  24                               // 8 uints
#define OFF_CNT    32                               // B*32768 floats
#define OFF_IDX    (OFF_CNT + BATCH*RCELLS)         // B*N ints
#define OFF_NORM   (OFF_IDX + BATCH*NPTS)           // B*3*N floats
#define OFF_BN     (OFF_NORM + BATCH*3*NPTS)        // 4*64 floats
#define OFF_WP1    (OFF_BN + 256)                   // 110592 f16 = 55296 floats
#define OFF_WP2    (OFF_WP1 + 55296)
#define OFF_G1     (OFF_WP2 + 55296)                // B*64*32768 fp32 (ch-major)
#define OFF_GA     (OFF_G1 + BATCH*CH*RCELLS)       // 16777216 f16 = 8388608 floats
#define OFF_GB     (OFF_GA + 8388608)

__device__ inline float waveReduceSum(float v) {
#pragma unroll
    for (int off = 32; off > 0; off >>= 1) v += __shfl_down(v, off, 64);
    return v;
}
__device__ inline float waveReduceMax(float v) {
#pragma unroll
    for (int off = 32; off > 0; off >>= 1) v = fmaxf(v, __shfl_down(v, off, 64));
    return v;
}

// ---------------- per-batch coordinate sums ----------------
__global__ __launch_bounds__(256) void k_stats_sum(const float* __restrict__ coords,
                                                   float* __restrict__ sums) {
    __shared__ float sm[3][4];
    int b = blockIdx.x >> 3, chunk = blockIdx.x & 7;
    const float* cb = coords + (size_t)b * 3 * NPTS;
    float s0 = 0.f, s1 = 0.f, s2 = 0.f;
    for (int i = threadIdx.x; i < 8192; i += 256) {
        int n = chunk * 8192 + i;
        s0 += cb[n];
        s1 += cb[n + NPTS];
        s2 += cb[n + 2 * NPTS];
    }
    s0 = waveReduceSum(s0); s1 = waveReduceSum(s1); s2 = waveReduceSum(s2);
    int lane = threadIdx.x & 63, wid = threadIdx.x >> 6;
    if (lane == 0) { sm[0][wid] = s0; sm[1][wid] = s1; sm[2][wid] = s2; }
    __syncthreads();
    if (threadIdx.x == 0) {
        atomicAdd(&sums[b * 3 + 0], sm[0][0] + sm[0][1] + sm[0][2] + sm[0][3]);
        atomicAdd(&sums[b * 3 + 1], sm[1][0] + sm[1][1] + sm[1][2] + sm[1][3]);
        atomicAdd(&sums[b * 3 + 2], sm[2][0] + sm[2][1] + sm[2][2] + sm[2][3]);
    }
}

// ---------------- per-batch max ||coord - mean|| ----------------
__global__ __launch_bounds__(256) void k_stats_max(const float* __restrict__ coords,
                                                   const float* __restrict__ sums,
                                                   unsigned int* __restrict__ scaleBits) {
    __shared__ float sm[4];
    int b = blockIdx.x >> 3, chunk = blockIdx.x & 7;
    const float* cb = coords + (size_t)b * 3 * NPTS;
    float mx = sums[b * 3 + 0] * (1.f / NPTS);
    float my = sums[b * 3 + 1] * (1.f / NPTS);
    float mz = sums[b * 3 + 2] * (1.f / NPTS);
    float m = 0.f;
    for (int i = threadIdx.x; i < 8192; i += 256) {
        int n = chunk * 8192 + i;
        float dx = cb[n] - mx, dy = cb[n + NPTS] - my, dz = cb[n + 2 * NPTS] - mz;
        m = fmaxf(m, sqrtf(dx * dx + dy * dy + dz * dz));
    }
    m = waveReduceMax(m);
    int lane = threadIdx.x & 63, wid = threadIdx.x >> 6;
    if (lane == 0) sm[wid] = m;
    __syncthreads();
    if (threadIdx.x == 0) {
        float r = fmaxf(fmaxf(sm[0], sm[1]), fmaxf(sm[2], sm[3]));
        atomicMax(&scaleBits[b], __float_as_uint(r));
    }
}

// ---------------- normalized coords, voxel index, counts ----------------
__global__ __launch_bounds__(256) void k_vox_assign(const float* __restrict__ coords,
                                                    const float* __restrict__ sums,
                                                    const unsigned int* __restrict__ scaleBits,
                                                    float* __restrict__ normc,
                                                    int* __restrict__ idxb,
                                                    float* __restrict__ cnt) {
    int g = blockIdx.x * 256 + threadIdx.x;       // 0 .. B*N-1
    int b = g >> 16, n = g & (NPTS - 1);
    const float* cb = coords + (size_t)b * 3 * NPTS;
    float scale2 = __uint_as_float(scaleBits[b]) * 2.f;
    int v[3];
#pragma unroll
    for (int d = 0; d < 3; ++d) {
        float mean = sums[b * 3 + d] * (1.f / NPTS);
        float x = (cb[d * NPTS + n] - mean) / scale2 + 0.5f;
        x *= (float)RES;
        x = fminf(fmaxf(x, 0.f), (float)(RES - 1));
        normc[(size_t)b * 3 * NPTS + d * NPTS + n] = x;
        v[d] = (int)rintf(x);
    }
    int id = (v[0] * RES + v[1]) * RES + v[2];
    idxb[b * NPTS + n] = id;
    atomicAdd(&cnt[b * RCELLS + id], 1.f);
}

// ---------------- weight repack (f16, MFMA A-layout) + BN constants ----------
// wP[s], s = ((tap*2+ct)*64 + co)*32 + ci_in  with ci = ct*32+ci_in
__global__ __launch_bounds__(256) void k_prep(const float* __restrict__ w,
                                              const float* __restrict__ bias,
                                              const float* __restrict__ g,
                                              const float* __restrict__ be,
                                              const float* __restrict__ m,
                                              const float* __restrict__ v,
                                              _Float16* __restrict__ wP,
                                              float* __restrict__ bnA,
                                              float* __restrict__ bnB) {
    int s = blockIdx.x * 256 + threadIdx.x;       // 0 .. 110591
    int ci_in = s & 31;
    int t  = s >> 5;
    int co = t & 63;
    int tc = t >> 6;                               // tap*2 + ct
    int ct = tc & 1;
    int tap = tc >> 1;
    int ci = ct * 32 + ci_in;
    wP[s] = (_Float16)w[co * 1728 + ci * 27 + tap];
    if (s < 64) {
        float A = g[s] / sqrtf(v[s] + BN_EPS);
        bnA[s] = A;
        bnB[s] = (bias[s] - m[s]) * A + be[s];
    }
}

// ---------------- scatter-average into voxel grid (fp32, ch-major) ----------
__global__ __launch_bounds__(256) void k_scatter(const float* __restrict__ features,
                                                 const int* __restrict__ idxb,
                                                 const float* __restrict__ cnt,
                                                 float* __restrict__ grid) {
    __shared__ float cells[16384];                 // 64 KiB
    int bc = blockIdx.x >> 1;
    int half = blockIdx.x & 1;
    int b = bc >> 6, c = bc & 63;
    int tid = threadIdx.x;
    for (int i = tid; i < 16384; i += 256) cells[i] = 0.f;
    __syncthreads();
    const float* f = features + ((size_t)b * CH + c) * NPTS;
    const int* id = idxb + b * NPTS;
    int lo = half * 16384;
    for (int n = tid; n < NPTS; n += 256) {
        int cell = id[n] - lo;
        if ((unsigned)cell < 16384u) atomicAdd(&cells[cell], f[n]);
    }
    __syncthreads();
    const float* cb = cnt + b * RCELLS + lo;
    float* gout = grid + ((size_t)b * CH + c) * RCELLS + lo;
    for (int i = tid; i < 16384; i += 256)
        gout[i] = cells[i] / fmaxf(cb[i], 1.f);
}

// ---------------- fp32 ch-major -> f16 channels-last [b][ct][cell][32] -------
__global__ __launch_bounds__(256) void k_cvt(const float* __restrict__ grid,
                                             _Float16* __restrict__ gA) {
    int g = blockIdx.x * 256 + threadIdx.x;        // 0 .. B*RCELLS-1
    int b = g >> 15, cell = g & (RCELLS - 1);
    const float* src = grid + (size_t)b * CH * RCELLS + cell;
#pragma unroll
    for (int ct = 0; ct < 2; ++ct) {
        f16x8 hv[4];
#pragma unroll
        for (int k = 0; k < 4; ++k)
#pragma unroll
            for (int j = 0; j < 8; ++j)
                hv[k][j] = (_Float16)src[(size_t)(ct * 32 + k * 8 + j) * RCELLS];
        _Float16* dst = gA + ((size_t)(b * 2 + ct) * RCELLS + cell) * 32;
#pragma unroll
        for (int k = 0; k < 4; ++k)
            *(f16x8*)(dst + k * 8) = hv[k];
    }
}

// ---------------- 3x3x3 conv via f16 MFMA (implicit shift-GEMM) -------------
// gIn/gOut layout: [b][ct(2)][z][y][x][ci(32)] f16.
// Block: (b, z, ygroup of 8 rows). 4 waves; wave w handles y rows {2w, 2w+1},
// all 64 co. Per wave: 4 co-tiles x 4 vox-tiles of 16x16, K = 2ct x 27tap x 32.
__global__ __launch_bounds__(256, 2) void k_conv(const _Float16* __restrict__ gIn,
                                                 _Float16* __restrict__ gOut,
                                                 const _Float16* __restrict__ wP,
                                                 const float* __restrict__ bnA,
                                                 const float* __restrict__ bnB) {
    __shared__ _Float16 sIn[3 * 10 * 34 * 32];     // 65280 B, halo-padded
    int bi = blockIdx.x;
    int b  = bi >> 7;
    int rem = bi & 127;
    int z  = rem >> 2;
    int yg = rem & 3;
    int tid = threadIdx.x;
    int wid = tid >> 6;
    int lane = tid & 63;
    int l15 = lane & 15, quad = lane >> 4;

    f32x4 acc[4][4];
#pragma unroll
    for (int mt = 0; mt < 4; ++mt)
#pragma unroll
        for (int nt = 0; nt < 4; ++nt) acc[mt][nt] = (f32x4){0.f, 0.f, 0.f, 0.f};

    const f16x8* wp8 = (const f16x8*)wP;

    // per-nt LDS base (center tap position), in f16 elements
    int bbase[4];
#pragma unroll
    for (int nt = 0; nt < 4; ++nt) {
        int yl = 2 * wid + (nt >> 1);
        int x  = ((nt & 1) << 4) + l15;
        bbase[nt] = ((10 + (yl + 1)) * 34 + (x + 1)) * 32 + quad * 8; // zz=1 center
    }

    for (int ct = 0; ct < 2; ++ct) {
        // ---- stage input tile [3z][10y][34x][32ci] with zero halos ----
        const _Float16* gin = gIn + (size_t)(b * 2 + ct) * (RCELLS * 32);
#pragma unroll
        for (int it = 0; it < 16; ++it) {
            int s = tid + it * 256;                 // 16B chunk id
            if (s < 4080) {
                int cc  = s & 3;
                int pos = s >> 2;                   // 0..1019
                int xx  = pos % 34;
                int t2  = pos / 34;
                int yy  = t2 % 10;
                int zz  = t2 / 10;
                int x = xx - 1, y = yg * 8 + yy - 1, z0 = z + zz - 1;
                f32x4 val = {0.f, 0.f, 0.f, 0.f};
                if ((unsigned)x < 32u && (unsigned)y < 32u && (unsigned)z0 < 32u)
                    val = *(const f32x4*)(gin + ((size_t)((z0 * 32 + y) * 32 + x)) * 32 + cc * 8);
                *(f32x4*)(sIn + (size_t)s * 8) = val;
            }
        }
        __syncthreads();

        // ---- 27 taps, each one 16x16x32 MFMA per (co-tile, vox-tile) ----
#pragma unroll
        for (int dz = -1; dz <= 1; ++dz)
#pragma unroll
        for (int dy = -1; dy <= 1; ++dy)
#pragma unroll
        for (int dx = -1; dx <= 1; ++dx) {
            int tap = (dz + 1) * 9 + (dy + 1) * 3 + (dx + 1);
            f16x8 aF[4];
#pragma unroll
            for (int mt = 0; mt < 4; ++mt)
                aF[mt] = wp8[tap * 512 + ct * 256 + mt * 64 + l15 * 4 + quad];
            f16x8 bF[4];
            int off = ((dz + 1) * 340 + dy * 34 + dx) * 32 - 340 * 32; // rel to center
#pragma unroll
            for (int nt = 0; nt < 4; ++nt)
                bF[nt] = *(const f16x8*)(sIn + bbase[nt] + off);
#pragma unroll
            for (int mt = 0; mt < 4; ++mt)
#pragma unroll
                for (int nt = 0; nt < 4; ++nt)
                    acc[mt][nt] = __builtin_amdgcn_mfma_f32_16x16x32_f16(
                        aF[mt], bF[nt], acc[mt][nt], 0, 0, 0);
        }
        __syncthreads();
    }

    // ---- epilogue: BN + LeakyReLU, store f16 channels-last ----
#pragma unroll
    for (int nt = 0; nt < 4; ++nt) {
        int y = yg * 8 + 2 * wid + (nt >> 1);
        int x = ((nt & 1) << 4) + l15;
        int cell = z * 1024 + y * 32 + x;
#pragma unroll
        for (int mt = 0; mt < 4; ++mt) {
            int cob = mt * 16 + quad * 4;           // 4 consecutive co
            f32x4 An = *(const f32x4*)(bnA + cob);
            f32x4 Bn = *(const f32x4*)(bnB + cob);
            f16x4 hv;
#pragma unroll
            for (int r = 0; r < 4; ++r) {
                float t = acc[mt][nt][r] * An[r] + Bn[r];
                t = (t >= 0.f) ? t : NEG_SLOPE * t;
                hv[r] = (_Float16)t;
            }
            _Float16* op = gOut + ((size_t)(b * 2 + (cob >> 5)) * RCELLS + cell) * 32 + (cob & 31);
            *(f16x4*)op = hv;
        }
    }
}

// ---------------- trilinear devoxelize (reads f16 channels-last) ------------
__global__ __launch_bounds__(256) void k_devox(const _Float16* __restrict__ gA,
                                               const float* __restrict__ normc,
                                               float* __restrict__ out) {
    int g = blockIdx.x * 256 + threadIdx.x;        // 0 .. B*N-1
    int b = g >> 16, n = g & (NPTS - 1);
    const float* nb = normc + (size_t)b * 3 * NPTS;
    float tx = nb[n], ty = nb[NPTS + n], tz = nb[2 * NPTS + n];
    float lx = floorf(tx), ly = floorf(ty), lz = floorf(tz);
    float fx = tx - lx, fy = ty - ly, fz = tz - lz;
    int x0 = (int)lx, y0 = (int)ly, z0 = (int)lz;
    int x1 = min(x0 + 1, RES - 1), y1 = min(y0 + 1, RES - 1), z1 = min(z0 + 1, RES - 1);
    int ids[8];
    float wc[8];
    ids[0] = (x0 * RES + y0) * RES + z0;
    ids[1] = (x0 * RES + y0) * RES + z1;
    ids[2] = (x0 * RES + y1) * RES + z0;
    ids[3] = (x0 * RES + y1) * RES + z1;
    ids[4] = (x1 * RES + y0) * RES + z0;
    ids[5] = (x1 * RES + y0) * RES + z1;
    ids[6] = (x1 * RES + y1) * RES + z0;
    ids[7] = (x1 * RES + y1) * RES + z1;
    float gx = 1.f - fx, gy = 1.f - fy, gz = 1.f - fz;
    wc[0] = gx * gy * gz; wc[1] = gx * gy * fz;
    wc[2] = gx * fy * gz; wc[3] = gx * fy * fz;
    wc[4] = fx * gy * gz; wc[5] = fx * gy * fz;
    wc[6] = fx * fy * gz; wc[7] = fx * fy * fz;

#pragma unroll
    for (int ct = 0; ct < 2; ++ct) {
        float acc[32];
#pragma unroll
        for (int j = 0; j < 32; ++j) acc[j] = 0.f;
        const _Float16* gb = gA + (size_t)(b * 2 + ct) * RCELLS * 32;
#pragma unroll
        for (int c8 = 0; c8 < 8; ++c8) {
            const _Float16* p = gb + (size_t)ids[c8] * 32;
            float wgt = wc[c8];
#pragma unroll
            for (int k = 0; k < 4; ++k) {
                f16x8 v = *(const f16x8*)(p + k * 8);
#pragma unroll
                for (int j = 0; j < 8; ++j)
                    acc[k * 8 + j] += wgt * (float)v[j];
            }
        }
        float* ob = out + (size_t)b * CH * NPTS + (size_t)(ct * 32) * NPTS + n;
#pragma unroll
        for (int j = 0; j < 32; ++j)
            ob[(size_t)j * NPTS] = acc[j];
    }
}

extern "C" void kernel_launch(void* const* d_in, const int* in_sizes, int n_in,
                              void* d_out, int out_size, void* d_ws, size_t ws_size,
                              hipStream_t stream) {
    const float* features = (const float*)d_in[0];
    const float* coords   = (const float*)d_in[1];
    const float* w1  = (const float*)d_in[2];
    const float* b1  = (const float*)d_in[3];
    const float* g1  = (const float*)d_in[4];
    const float* be1 = (const float*)d_in[5];
    const float* m1  = (const float*)d_in[6];
    const float* v1  = (const float*)d_in[7];
    const float* w2  = (const float*)d_in[8];
    const float* b2  = (const float*)d_in[9];
    const float* g2  = (const float*)d_in[10];
    const float* be2 = (const float*)d_in[11];
    const float* m2  = (const float*)d_in[12];
    const float* v2  = (const float*)d_in[13];

    float* ws = (float*)d_ws;
    float*        sums      = ws + OFF_SUMS;
    unsigned int* scaleBits = (unsigned int*)(ws + OFF_SCALE);
    float*        cnt       = ws + OFF_CNT;
    int*          idxb      = (int*)(ws + OFF_IDX);
    float*        normc     = ws + OFF_NORM;
    float*        bnA1      = ws + OFF_BN;
    float*        bnB1      = ws + OFF_BN + 64;
    float*        bnA2      = ws + OFF_BN + 128;
    float*        bnB2      = ws + OFF_BN + 192;
    _Float16*     wP1       = (_Float16*)(ws + OFF_WP1);
    _Float16*     wP2       = (_Float16*)(ws + OFF_WP2);
    float*        grid1     = ws + OFF_G1;
    _Float16*     gA        = (_Float16*)(ws + OFF_GA);
    _Float16*     gB        = (_Float16*)(ws + OFF_GB);

    // zero: sums + scaleBits + cnt
    hipMemsetAsync(ws, 0, (size_t)(OFF_CNT + BATCH * RCELLS) * sizeof(float), stream);

    k_stats_sum<<<64, 256, 0, stream>>>(coords, sums);
    k_stats_max<<<64, 256, 0, stream>>>(coords, sums, scaleBits);
    k_vox_assign<<<(BATCH * NPTS) / 256, 256, 0, stream>>>(coords, sums, scaleBits,
                                                           normc, idxb, cnt);
    k_prep<<<432, 256, 0, stream>>>(w1, b1, g1, be1, m1, v1, wP1, bnA1, bnB1);
    k_prep<<<432, 256, 0, stream>>>(w2, b2, g2, be2, m2, v2, wP2, bnA2, bnB2);
    k_scatter<<<BATCH * CH * 2, 256, 0, stream>>>(features, idxb, cnt, grid1);
    k_cvt<<<(BATCH * RCELLS) / 256, 256, 0, stream>>>(grid1, gA);
    k_conv<<<BATCH * RES * 4, 256, 0, stream>>>(gA, gB, wP1, bnA1, bnB1);
    k_conv<<<BATCH * RES * 4, 256, 0, stream>>>(gB, gA, wP2, bnA2, bnB2);
    k_devox<<<(BATCH * NPTS) / 256, 256, 0, stream>>>(gA, normc, (float*)d_out);

    // append passthrough coords
    hipMemcpyAsync((float*)d_out + (size_t)BATCH * CH * NPTS, coords,
                   (size_t)BATCH * 3 * NPTS * sizeof(float),
                   hipMemcpyDeviceToDevice, stream);
}

// Round 3
// 853.522 us; speedup vs baseline: 3.8716x; 1.1565x over previous
//
#include <hip/hip_runtime.h>
#include <hip/hip_bf16.h>

// Problem constants
#define NPTS   65536
#define BATCH  8
#define CH     64
#define RES    32
#define RCELLS 32768          // 32^3
#define NEG_SLOPE 0.1f
#define BN_EPS 1e-4f

typedef float    f32x4 __attribute__((ext_vector_type(4)));
typedef _Float16 f16x8 __attribute__((ext_vector_type(8)));
typedef _Float16 f16x4 __attribute__((ext_vector_type(4)));

// Workspace layout (float offsets)
#define OFF_SUMS   0                                 // 24 floats
#define OFF_SCALE  24                                // 8 uints
#define OFF_CNT    32                                // B*32768 ints (zeroed)
#define OFF_IDX    (OFF_CNT + BATCH*RCELLS)          // B*N ints
#define OFF_CSTART (OFF_IDX + BATCH*NPTS)            // B*32768 ints
#define OFF_ORDER  (OFF_CSTART + BATCH*RCELLS)       // B*N ints
#define OFF_BN     (OFF_ORDER + BATCH*NPTS)          // 4*64 floats
#define OFF_WP1    (OFF_BN + 256)                    // 110592 f16 = 55296 fl
#define OFF_WP2    (OFF_WP1 + 55296)
#define OFF_FT     (OFF_WP2 + 55296)                 // B*N*64 f16 = 16777216 fl
#define OFF_GA     (OFF_FT + 16777216)               // 16777216 f16 = 8388608 fl
#define OFF_GB     (OFF_GA + 8388608)

__device__ inline float waveReduceSum(float v) {
#pragma unroll
    for (int off = 32; off > 0; off >>= 1) v += __shfl_down(v, off, 64);
    return v;
}
__device__ inline float waveReduceMax(float v) {
#pragma unroll
    for (int off = 32; off > 0; off >>= 1) v = fmaxf(v, __shfl_down(v, off, 64));
    return v;
}

// ---------------- per-batch coordinate sums ----------------
__global__ __launch_bounds__(256) void k_stats_sum(const float* __restrict__ coords,
                                                   float* __restrict__ sums) {
    __shared__ float sm[3][4];
    int b = blockIdx.x >> 3, chunk = blockIdx.x & 7;
    const float* cb = coords + (size_t)b * 3 * NPTS;
    float s0 = 0.f, s1 = 0.f, s2 = 0.f;
    for (int i = threadIdx.x; i < 8192; i += 256) {
        int n = chunk * 8192 + i;
        s0 += cb[n];
        s1 += cb[n + NPTS];
        s2 += cb[n + 2 * NPTS];
    }
    s0 = waveReduceSum(s0); s1 = waveReduceSum(s1); s2 = waveReduceSum(s2);
    int lane = threadIdx.x & 63, wid = threadIdx.x >> 6;
    if (lane == 0) { sm[0][wid] = s0; sm[1][wid] = s1; sm[2][wid] = s2; }
    __syncthreads();
    if (threadIdx.x == 0) {
        atomicAdd(&sums[b * 3 + 0], sm[0][0] + sm[0][1] + sm[0][2] + sm[0][3]);
        atomicAdd(&sums[b * 3 + 1], sm[1][0] + sm[1][1] + sm[1][2] + sm[1][3]);
        atomicAdd(&sums[b * 3 + 2], sm[2][0] + sm[2][1] + sm[2][2] + sm[2][3]);
    }
}

// ---------------- per-batch max ||coord - mean|| ----------------
__global__ __launch_bounds__(256) void k_stats_max(const float* __restrict__ coords,
                                                   const float* __restrict__ sums,
                                                   unsigned int* __restrict__ scaleBits) {
    __shared__ float sm[4];
    int b = blockIdx.x >> 3, chunk = blockIdx.x & 7;
    const float* cb = coords + (size_t)b * 3 * NPTS;
    float mx = sums[b * 3 + 0] * (1.f / NPTS);
    float my = sums[b * 3 + 1] * (1.f / NPTS);
    float mz = sums[b * 3 + 2] * (1.f / NPTS);
    float m = 0.f;
    for (int i = threadIdx.x; i < 8192; i += 256) {
        int n = chunk * 8192 + i;
        float dx = cb[n] - mx, dy = cb[n + NPTS] - my, dz = cb[n + 2 * NPTS] - mz;
        m = fmaxf(m, sqrtf(dx * dx + dy * dy + dz * dz));
    }
    m = waveReduceMax(m);
    int lane = threadIdx.x & 63, wid = threadIdx.x >> 6;
    if (lane == 0) sm[wid] = m;
    __syncthreads();
    if (threadIdx.x == 0) {
        float r = fmaxf(fmaxf(sm[0], sm[1]), fmaxf(sm[2], sm[3]));
        atomicMax(&scaleBits[b], __float_as_uint(r));
    }
}

// ---------------- voxel index + int counts ----------------
__global__ __launch_bounds__(256) void k_vox_assign(const float* __restrict__ coords,
                                                    const float* __restrict__ sums,
                                                    const unsigned int* __restrict__ scaleBits,
                                                    int* __restrict__ idxb,
                                                    int* __restrict__ cnt) {
    int g = blockIdx.x * 256 + threadIdx.x;       // 0 .. B*N-1
    int b = g >> 16, n = g & (NPTS - 1);
    const float* cb = coords + (size_t)b * 3 * NPTS;
    float scale2 = __uint_as_float(scaleBits[b]) * 2.f;
    int v[3];
#pragma unroll
    for (int d = 0; d < 3; ++d) {
        float mean = sums[b * 3 + d] * (1.f / NPTS);
        float x = (cb[d * NPTS + n] - mean) / scale2 + 0.5f;
        x *= (float)RES;
        x = fminf(fmaxf(x, 0.f), (float)(RES - 1));
        v[d] = (int)rintf(x);
    }
    int id = (v[0] * RES + v[1]) * RES + v[2];
    idxb[b * NPTS + n] = id;
    atomicAdd(&cnt[b * RCELLS + id], 1);
}

// ---------------- per-batch exclusive prefix scan of cell counts ------------
__global__ __launch_bounds__(256) void k_scan(const int* __restrict__ cnt,
                                              int* __restrict__ cellStart) {
    __shared__ int bufA[256], bufB[256];
    int b = blockIdx.x, tid = threadIdx.x;
    const int* cb = cnt + b * RCELLS;
    int sum = 0;
    for (int i = 0; i < 128; ++i) sum += cb[tid * 128 + i];
    bufA[tid] = sum;
    __syncthreads();
    int* src = bufA; int* dst = bufB;
    for (int off = 1; off < 256; off <<= 1) {
        int v = src[tid];
        if (tid >= off) v += src[tid - off];
        dst[tid] = v;
        __syncthreads();
        int* t = src; src = dst; dst = t;
    }
    int run = (tid > 0) ? src[tid - 1] : 0;        // exclusive
    int* cs = cellStart + b * RCELLS;
    for (int i = 0; i < 128; ++i) {
        int c = cb[tid * 128 + i];
        cs[tid * 128 + i] = run;
        run += c;
    }
}

// ---------------- rank points into cell-sorted order ----------------
// Mutates cellStart: afterwards cellStart[c] == end offset of cell c.
__global__ __launch_bounds__(256) void k_rank(const int* __restrict__ idxb,
                                              int* __restrict__ cellStart,
                                              int* __restrict__ order) {
    int g = blockIdx.x * 256 + threadIdx.x;
    int b = g >> 16, n = g & (NPTS - 1);
    int cell = idxb[b * NPTS + n];
    int pos = atomicAdd(&cellStart[b * RCELLS + cell], 1);
    order[b * NPTS + pos] = n;
}

// ---------------- features fp32 [b][c][n] -> f16 [b][n][64] ----------------
__global__ __launch_bounds__(256) void k_transpose(const float* __restrict__ f,
                                                   _Float16* __restrict__ featT) {
    int g = blockIdx.x * 256 + threadIdx.x;        // 0 .. B*N-1
    int b = g >> 16, n = g & (NPTS - 1);
    const float* fb = f + (size_t)b * CH * NPTS + n;
    _Float16* dst = featT + (size_t)g * 64;
#pragma unroll
    for (int k = 0; k < 8; ++k) {
        f16x8 hv;
#pragma unroll
        for (int j = 0; j < 8; ++j)
            hv[j] = (_Float16)fb[(size_t)(k * 8 + j) * NPTS];
        *(f16x8*)(dst + k * 8) = hv;
    }
}

// ---------------- gather-average into f16 channels-last grid ----------------
// gA layout: [b][ct(2)][cell][32] f16. One thread per (b, cell, ct).
__global__ __launch_bounds__(256) void k_gather(const _Float16* __restrict__ featT,
                                                const int* __restrict__ order,
                                                const int* __restrict__ cellStart,
                                                const int* __restrict__ cnt,
                                                _Float16* __restrict__ gA) {
    int t = blockIdx.x * 256 + threadIdx.x;        // 0 .. B*RCELLS*2-1
    int b = t >> 16;
    int r = t & 65535;
    int cell = r >> 1;
    int ct = r & 1;
    int e = cellStart[b * RCELLS + cell];          // post-rank: end offset
    int c = cnt[b * RCELLS + cell];
    int s = e - c;
    float acc[32];
#pragma unroll
    for (int j = 0; j < 32; ++j) acc[j] = 0.f;
    const int* ob = order + b * NPTS;
    const _Float16* fb = featT + (((size_t)b << 16)) * 64 + ct * 32;
    for (int p = s; p < e; ++p) {
        int n = ob[p];
        const _Float16* q = fb + (size_t)n * 64;
#pragma unroll
        for (int k = 0; k < 4; ++k) {
            f16x8 v = *(const f16x8*)(q + k * 8);
#pragma unroll
            for (int j = 0; j < 8; ++j)
                acc[k * 8 + j] += (float)v[j];
        }
    }
    float inv = 1.f / (float)max(c, 1);
    _Float16* dst = gA + ((size_t)(b * 2 + ct) * RCELLS + cell) * 32;
#pragma unroll
    for (int k = 0; k < 4; ++k) {
        f16x8 hv;
#pragma unroll
        for (int j = 0; j < 8; ++j)
            hv[j] = (_Float16)(acc[k * 8 + j] * inv);
        *(f16x8*)(dst + k * 8) = hv;
    }
}

// ---------------- weight repack (f16, MFMA A-layout) + BN constants ----------
__global__ __launch_bounds__(256) void k_prep(const float* __restrict__ w,
                                              const float* __restrict__ bias,
                                              const float* __restrict__ g,
                                              const float* __restrict__ be,
                                              const float* __restrict__ m,
                                              const float* __restrict__ v,
                                              _Float16* __restrict__ wP,
                                              float* __restrict__ bnA,
                                              float* __restrict__ bnB) {
    int s = blockIdx.x * 256 + threadIdx.x;       // 0 .. 110591
    int ci_in = s & 31;
    int t  = s >> 5;
    int co = t & 63;
    int tc = t >> 6;                               // tap*2 + ct
    int ct = tc & 1;
    int tap = tc >> 1;
    int ci = ct * 32 + ci_in;
    wP[s] = (_Float16)w[co * 1728 + ci * 27 + tap];
    if (s < 64) {
        float A = g[s] / sqrtf(v[s] + BN_EPS);
        bnA[s] = A;
        bnB[s] = (bias[s] - m[s]) * A + be[s];
    }
}

// ---------------- 3x3x3 conv via f16 MFMA (implicit shift-GEMM) -------------
__global__ __launch_bounds__(256, 2) void k_conv(const _Float16* __restrict__ gIn,
                                                 _Float16* __restrict__ gOut,
                                                 const _Float16* __restrict__ wP,
                                                 const float* __restrict__ bnA,
                                                 const float* __restrict__ bnB) {
    __shared__ _Float16 sIn[3 * 10 * 34 * 32];     // 65280 B, halo-padded
    int bi = blockIdx.x;
    int b  = bi >> 7;
    int rem = bi & 127;
    int z  = rem >> 2;
    int yg = rem & 3;
    int tid = threadIdx.x;
    int wid = tid >> 6;
    int lane = tid & 63;
    int l15 = lane & 15, quad = lane >> 4;

    f32x4 acc[4][4];
#pragma unroll
    for (int mt = 0; mt < 4; ++mt)
#pragma unroll
        for (int nt = 0; nt < 4; ++nt) acc[mt][nt] = (f32x4){0.f, 0.f, 0.f, 0.f};

    const f16x8* wp8 = (const f16x8*)wP;

    int bbase[4];
#pragma unroll
    for (int nt = 0; nt < 4; ++nt) {
        int yl = 2 * wid + (nt >> 1);
        int x  = ((nt & 1) << 4) + l15;
        bbase[nt] = ((10 + (yl + 1)) * 34 + (x + 1)) * 32 + quad * 8; // zz=1
    }

    for (int ct = 0; ct < 2; ++ct) {
        const _Float16* gin = gIn + (size_t)(b * 2 + ct) * (RCELLS * 32);
#pragma unroll
        for (int it = 0; it < 16; ++it) {
            int s = tid + it * 256;                 // 16B chunk id
            if (s < 4080) {
                int cc  = s & 3;
                int pos = s >> 2;                   // 0..1019
                int xx  = pos % 34;
                int t2  = pos / 34;
                int yy  = t2 % 10;
                int zz  = t2 / 10;
                int x = xx - 1, y = yg * 8 + yy - 1, z0 = z + zz - 1;
                f32x4 val = {0.f, 0.f, 0.f, 0.f};
                if ((unsigned)x < 32u && (unsigned)y < 32u && (unsigned)z0 < 32u)
                    val = *(const f32x4*)(gin + ((size_t)((z0 * 32 + y) * 32 + x)) * 32 + cc * 8);
                *(f32x4*)(sIn + (size_t)s * 8) = val;
            }
        }
        __syncthreads();

#pragma unroll
        for (int dz = -1; dz <= 1; ++dz)
#pragma unroll
        for (int dy = -1; dy <= 1; ++dy)
#pragma unroll
        for (int dx = -1; dx <= 1; ++dx) {
            int tap = (dz + 1) * 9 + (dy + 1) * 3 + (dx + 1);
            f16x8 aF[4];
#pragma unroll
            for (int mt = 0; mt < 4; ++mt)
                aF[mt] = wp8[tap * 512 + ct * 256 + mt * 64 + l15 * 4 + quad];
            f16x8 bF[4];
            int off = ((dz + 1) * 340 + dy * 34 + dx) * 32 - 340 * 32;
#pragma unroll
            for (int nt = 0; nt < 4; ++nt)
                bF[nt] = *(const f16x8*)(sIn + bbase[nt] + off);
#pragma unroll
            for (int mt = 0; mt < 4; ++mt)
#pragma unroll
                for (int nt = 0; nt < 4; ++nt)
                    acc[mt][nt] = __builtin_amdgcn_mfma_f32_16x16x32_f16(
                        aF[mt], bF[nt], acc[mt][nt], 0, 0, 0);
        }
        __syncthreads();
    }

#pragma unroll
    for (int nt = 0; nt < 4; ++nt) {
        int y = yg * 8 + 2 * wid + (nt >> 1);
        int x = ((nt & 1) << 4) + l15;
        int cell = z * 1024 + y * 32 + x;
#pragma unroll
        for (int mt = 0; mt < 4; ++mt) {
            int cob = mt * 16 + quad * 4;           // 4 consecutive co
            f32x4 An = *(const f32x4*)(bnA + cob);
            f32x4 Bn = *(const f32x4*)(bnB + cob);
            f16x4 hv;
#pragma unroll
            for (int r = 0; r < 4; ++r) {
                float t = acc[mt][nt][r] * An[r] + Bn[r];
                t = (t >= 0.f) ? t : NEG_SLOPE * t;
                hv[r] = (_Float16)t;
            }
            _Float16* op = gOut + ((size_t)(b * 2 + (cob >> 5)) * RCELLS + cell) * 32 + (cob & 31);
            *(f16x4*)op = hv;
        }
    }
}

// ---------------- trilinear devoxelize (recomputes norm coords) -------------
__global__ __launch_bounds__(256) void k_devox(const _Float16* __restrict__ gA,
                                               const float* __restrict__ coords,
                                               const float* __restrict__ sums,
                                               const unsigned int* __restrict__ scaleBits,
                                               float* __restrict__ out) {
    int g = blockIdx.x * 256 + threadIdx.x;        // 0 .. B*N-1
    int b = g >> 16, n = g & (NPTS - 1);
    const float* cb = coords + (size_t)b * 3 * NPTS;
    float scale2 = __uint_as_float(scaleBits[b]) * 2.f;
    float nc[3];
#pragma unroll
    for (int d = 0; d < 3; ++d) {
        float mean = sums[b * 3 + d] * (1.f / NPTS);
        float x = (cb[d * NPTS + n] - mean) / scale2 + 0.5f;
        x *= (float)RES;
        nc[d] = fminf(fmaxf(x, 0.f), (float)(RES - 1));
    }
    float tx = nc[0], ty = nc[1], tz = nc[2];
    float lx = floorf(tx), ly = floorf(ty), lz = floorf(tz);
    float fx = tx - lx, fy = ty - ly, fz = tz - lz;
    int x0 = (int)lx, y0 = (int)ly, z0 = (int)lz;
    int x1 = min(x0 + 1, RES - 1), y1 = min(y0 + 1, RES - 1), z1 = min(z0 + 1, RES - 1);
    int ids[8];
    float wc[8];
    ids[0] = (x0 * RES + y0) * RES + z0;
    ids[1] = (x0 * RES + y0) * RES + z1;
    ids[2] = (x0 * RES + y1) * RES + z0;
    ids[3] = (x0 * RES + y1) * RES + z1;
    ids[4] = (x1 * RES + y0) * RES + z0;
    ids[5] = (x1 * RES + y0) * RES + z1;
    ids[6] = (x1 * RES + y1) * RES + z0;
    ids[7] = (x1 * RES + y1) * RES + z1;
    float gx = 1.f - fx, gy = 1.f - fy, gz = 1.f - fz;
    wc[0] = gx * gy * gz; wc[1] = gx * gy * fz;
    wc[2] = gx * fy * gz; wc[3] = gx * fy * fz;
    wc[4] = fx * gy * gz; wc[5] = fx * gy * fz;
    wc[6] = fx * fy * gz; wc[7] = fx * fy * fz;

#pragma unroll
    for (int ct = 0; ct < 2; ++ct) {
        float acc[32];
#pragma unroll
        for (int j = 0; j < 32; ++j) acc[j] = 0.f;
        const _Float16* gb = gA + (size_t)(b * 2 + ct) * RCELLS * 32;
#pragma unroll
        for (int c8 = 0; c8 < 8; ++c8) {
            const _Float16* p = gb + (size_t)ids[c8] * 32;
            float wgt = wc[c8];
#pragma unroll
            for (int k = 0; k < 4; ++k) {
                f16x8 v = *(const f16x8*)(p + k * 8);
#pragma unroll
                for (int j = 0; j < 8; ++j)
                    acc[k * 8 + j] += wgt * (float)v[j];
            }
        }
        float* ob = out + (size_t)b * CH * NPTS + (size_t)(ct * 32) * NPTS + n;
#pragma unroll
        for (int j = 0; j < 32; ++j)
            ob[(size_t)j * NPTS] = acc[j];
    }
}

extern "C" void kernel_launch(void* const* d_in, const int* in_sizes, int n_in,
                              void* d_out, int out_size, void* d_ws, size_t ws_size,
                              hipStream_t stream) {
    const float* features = (const float*)d_in[0];
    const float* coords   = (const float*)d_in[1];
    const float* w1  = (const float*)d_in[2];
    const float* b1  = (const float*)d_in[3];
    const float* g1  = (const float*)d_in[4];
    const float* be1 = (const float*)d_in[5];
    const float* m1  = (const float*)d_in[6];
    const float* v1  = (const float*)d_in[7];
    const float* w2  = (const float*)d_in[8];
    const float* b2  = (const float*)d_in[9];
    const float* g2  = (const float*)d_in[10];
    const float* be2 = (const float*)d_in[11];
    const float* m2  = (const float*)d_in[12];
    const float* v2  = (const float*)d_in[13];

    float* ws = (float*)d_ws;
    float*        sums      = ws + OFF_SUMS;
    unsigned int* scaleBits = (unsigned int*)(ws + OFF_SCALE);
    int*          cnt       = (int*)(ws + OFF_CNT);
    int*          idxb      = (int*)(ws + OFF_IDX);
    int*          cellStart = (int*)(ws + OFF_CSTART);
    int*          order     = (int*)(ws + OFF_ORDER);
    float*        bnA1      = ws + OFF_BN;
    float*        bnB1      = ws + OFF_BN + 64;
    float*        bnA2      = ws + OFF_BN + 128;
    float*        bnB2      = ws + OFF_BN + 192;
    _Float16*     wP1       = (_Float16*)(ws + OFF_WP1);
    _Float16*     wP2       = (_Float16*)(ws + OFF_WP2);
    _Float16*     featT     = (_Float16*)(ws + OFF_FT);
    _Float16*     gA        = (_Float16*)(ws + OFF_GA);
    _Float16*     gB        = (_Float16*)(ws + OFF_GB);

    // zero: sums + scaleBits + cnt
    hipMemsetAsync(ws, 0, (size_t)(OFF_IDX) * sizeof(float), stream);

    k_stats_sum<<<64, 256, 0, stream>>>(coords, sums);
    k_stats_max<<<64, 256, 0, stream>>>(coords, sums, scaleBits);
    k_vox_assign<<<(BATCH * NPTS) / 256, 256, 0, stream>>>(coords, sums, scaleBits,
                                                           idxb, cnt);
    k_scan<<<BATCH, 256, 0, stream>>>(cnt, cellStart);
    k_rank<<<(BATCH * NPTS) / 256, 256, 0, stream>>>(idxb, cellStart, order);
    k_transpose<<<(BATCH * NPTS) / 256, 256, 0, stream>>>(features, featT);
    k_gather<<<(BATCH * RCELLS * 2) / 256, 256, 0, stream>>>(featT, order, cellStart,
                                                             cnt, gA);
    k_prep<<<432, 256, 0, stream>>>(w1, b1, g1, be1, m1, v1, wP1, bnA1, bnB1);
    k_prep<<<432, 256, 0, stream>>>(w2, b2, g2, be2, m2, v2, wP2, bnA2, bnB2);
    k_conv<<<BATCH * RES * 4, 256, 0, stream>>>(gA, gB, wP1, bnA1, bnB1);
    k_conv<<<BATCH * RES * 4, 256, 0, stream>>>(gB, gA, wP2, bnA2, bnB2);
    k_devox<<<(BATCH * NPTS) / 256, 256, 0, stream>>>(gA, coords, sums, scaleBits,
                                                      (float*)d_out);

    // append passthrough coords
    hipMemcpyAsync((float*)d_out + (size_t)BATCH * CH * NPTS, coords,
                   (size_t)BATCH * 3 * NPTS * sizeof(float),
                   hipMemcpyDeviceToDevice, stream);
}